// Round 36
// baseline (50.405 us; speedup 1.0000x reference)
//
#include <hip/hip_runtime.h>
#include <hip/hip_bf16.h>
#include <cstdint>

typedef unsigned short u16;
typedef __attribute__((ext_vector_type(8))) short short8;   // 8 bf16 = 4 VGPR
typedef __attribute__((ext_vector_type(4))) short short4v;  // 4 bf16 = 8B
typedef __attribute__((ext_vector_type(4))) float f32x4;

#define MFMA16(a, b, c) __builtin_amdgcn_mfma_f32_16x16x32_bf16((a), (b), (c), 0, 0, 0)

constexpr int Bn   = 16;
constexpr int Tn   = 2048;
constexpr int Cn   = 384;
constexpr int Hn   = 64;
constexpr long NTOK = (long)Bn * Tn;          // 32768
constexpr long NELT = NTOK * Hn;              // 2,097,152
constexpr int SPLITS = 2;                     // grid 512 = 1 round of 2 blocks/CU

// Q pre-scale: (1/sqrt(64)) * log2(e), so attention uses bare exp2
#define QSCALE 0.18033688011112042f

// f32 -> bf16 round-to-nearest-even
__device__ __forceinline__ u16 f2bf(float f) {
  union { float f; uint32_t u; } c; c.f = f;
  uint32_t u = c.u;
  return (u16)((u + 0x7fffu + ((u >> 16) & 1u)) >> 16);
}

// pack 2 f32 -> 2 bf16 in one u32 (RNE), gfx950 v_cvt_pk_bf16_f32
__device__ __forceinline__ uint32_t pkbf(float a, float b) {
  uint32_t d;
  asm("v_cvt_pk_bf16_f32 %0, %1, %2" : "=v"(d) : "v"(a), "v"(b));
  return d;
}

// load 8 consecutive f32 and pack to one bf16x8 A-fragment word
__device__ __forceinline__ short8 ldx8(const float* p) {
  const float4 f0 = *reinterpret_cast<const float4*>(p);
  const float4 f1 = *reinterpret_cast<const float4*>(p + 4);
  union { short8 s8; uint32_t u[4]; } r;
  r.u[0] = pkbf(f0.x, f0.y); r.u[1] = pkbf(f0.z, f0.w);
  r.u[2] = pkbf(f1.x, f1.y); r.u[3] = pkbf(f1.z, f1.w);
  return r.s8;
}

// async global->LDS, 16B per lane. LDS dest = wave-uniform base + lane*16.
__device__ __forceinline__ void gl16(const u16* g, const u16* l) {
  __builtin_amdgcn_global_load_lds(
      (const __attribute__((address_space(1))) void*)g,
      (__attribute__((address_space(3))) void*)l, 16, 0, 0);
}

// ---------------------------------------------------------------------------
// Kernel 0: W pre-transpose.  W[384][64] f32 (x3) -> WT[3][64][384] bf16.
// ---------------------------------------------------------------------------
__global__ __launch_bounds__(256) void wtrans(
    const float* __restrict__ Wq, const float* __restrict__ Wk,
    const float* __restrict__ Wv, u16* __restrict__ wtd)
{
  __shared__ u16 tile[64][65];
  const int m  = blockIdx.x / 6;
  const int kc = blockIdx.x % 6;
  const float* W = (m == 0) ? Wq : (m == 1) ? Wk : Wv;
  const int t = threadIdx.x;

  {
    const int kr = t >> 2, seg = t & 3;
    const float* src = W + (size_t)(kc * 64 + kr) * Hn + seg * 16;
    #pragma unroll
    for (int j = 0; j < 4; ++j) {
      const float4 f = *reinterpret_cast<const float4*>(src + j * 4);
      u16* p = &tile[kr][seg * 16 + j * 4];
      p[0] = f2bf(f.x); p[1] = f2bf(f.y); p[2] = f2bf(f.z); p[3] = f2bf(f.w);
    }
  }
  __syncthreads();
  {
    const int hr = t >> 2, seg = t & 3;
    union { short8 s; u16 u[8]; } o0, o1;
    #pragma unroll
    for (int j = 0; j < 8; ++j) o0.u[j] = tile[seg * 16 + j][hr];
    #pragma unroll
    for (int j = 0; j < 8; ++j) o1.u[j] = tile[seg * 16 + 8 + j][hr];
    u16* dst = wtd + ((size_t)m * 64 + hr) * Cn + kc * 64 + seg * 16;
    *reinterpret_cast<short8*>(dst)     = o0.s;
    *reinterpret_cast<short8*>(dst + 8) = o1.s;
  }
}

// ---------------------------------------------------------------------------
// Kernel 1: QKV projection: triple-buffered W gl16 + 2-deep x prefetch,
// counted vmcnt chain.  Grid 512 x 256; LDS 72 KB.
// ---------------------------------------------------------------------------
__global__ __launch_bounds__(256, 2) void qkv_proj(
    const float* __restrict__ x, const u16* __restrict__ wtd,
    const float* __restrict__ bq, const float* __restrict__ bk,
    const float* __restrict__ bv,
    u16* __restrict__ oq, u16* __restrict__ ok, u16* __restrict__ ovt)
{
  __shared__ u16 wbuf[3][3 * 64 * 64];   // 3 x 24 KB, swizzled granules

  const int t    = threadIdx.x;
  const int lane = t & 63;
  const int w    = t >> 6;
  const int l15  = lane & 15;
  const int lh   = lane >> 4;
  const long r0  = (long)blockIdx.x * 64;

  int srcoff[6];
  #pragma unroll
  for (int i = 0; i < 6; ++i) {
    const int g = i * 256 + t;
    const int r = g >> 3, c = g & 7;
    srcoff[i] = r * Cn + ((c ^ (r & 7)) << 3);
  }
  const int ldsb = w * 64 * 8;

  const float* xrow = x + (r0 + w * 16 + l15) * Cn;

  const int cks0 = ((lh)     ^ (l15 & 7)) << 3;
  const int cks1 = ((lh + 4) ^ (l15 & 7)) << 3;

  f32x4 acc[3][4];
  #pragma unroll
  for (int m = 0; m < 3; ++m)
    #pragma unroll
    for (int n = 0; n < 4; ++n) acc[m][n] = f32x4{0.f, 0.f, 0.f, 0.f};

  #pragma unroll
  for (int i = 0; i < 6; ++i)
    gl16(wtd + srcoff[i], &wbuf[0][(i * 256) * 8 + ldsb]);
  short8 aCur0 = ldx8(xrow + lh * 8);
  short8 aCur1 = ldx8(xrow + 32 + lh * 8);
  #pragma unroll
  for (int i = 0; i < 6; ++i)
    gl16(wtd + 64 + srcoff[i], &wbuf[1][(i * 256) * 8 + ldsb]);
  short8 aNx10 = ldx8(xrow + 64 + lh * 8);
  short8 aNx11 = ldx8(xrow + 96 + lh * 8);
  short8 aNx20, aNx21;
  asm volatile("s_waitcnt vmcnt(14)" ::: "memory");
  __builtin_amdgcn_s_barrier();
  __builtin_amdgcn_sched_barrier(0);

  for (int kc = 0; kc < 6; ++kc) {
    const int cb = kc % 3;
    const int sb = (kc + 2) % 3;
    if (kc + 2 < 6) {
      #pragma unroll
      for (int i = 0; i < 6; ++i)
        gl16(wtd + (kc + 2) * 64 + srcoff[i], &wbuf[sb][(i * 256) * 8 + ldsb]);
      const float* p = xrow + (kc + 2) * 64 + lh * 8;
      aNx20 = ldx8(p);
      aNx21 = ldx8(p + 32);
    }

    const u16* wc = &wbuf[cb][0];
    #pragma unroll
    for (int m = 0; m < 3; ++m)
      #pragma unroll
      for (int n = 0; n < 4; ++n) {
        const int row = m * 64 + n * 16 + l15;
        const short8 b0 = *reinterpret_cast<const short8*>(&wc[row * 64 + cks0]);
        acc[m][n] = MFMA16(aCur0, b0, acc[m][n]);
        const short8 b1 = *reinterpret_cast<const short8*>(&wc[row * 64 + cks1]);
        acc[m][n] = MFMA16(aCur1, b1, acc[m][n]);
      }

    if (kc + 1 < 6) {
      if (kc + 2 < 6) asm volatile("s_waitcnt vmcnt(14)" ::: "memory");
      else            asm volatile("s_waitcnt vmcnt(4)"  ::: "memory");
      __builtin_amdgcn_s_barrier();
      __builtin_amdgcn_sched_barrier(0);
      aCur0 = aNx10; aCur1 = aNx11;
      aNx10 = aNx20; aNx11 = aNx21;
    }
  }

  {
    const float* bias[2] = {bq, bk};
    u16*         dst[2]  = {oq, ok};
    const float  scl[2]  = {QSCALE, 1.0f};
    #pragma unroll
    for (int m = 0; m < 2; ++m) {
      #pragma unroll
      for (int n = 0; n < 4; ++n) {
        int col = n * 16 + l15;
        float bb = bias[m][col];
        #pragma unroll
        for (int r = 0; r < 4; ++r) {
          int row = lh * 4 + r;
          dst[m][(r0 + w * 16 + row) * Hn + col] = f2bf((acc[m][n][r] + bb) * scl[m]);
        }
      }
    }
  }
  {
    const long g    = r0 + w * 16 + lh * 4;
    const long bidx = g >> 11;
    const long tloc = g & 2047;
    const int  u    = (int)(tloc & 63);
    const long tb   = tloc & ~63L;
    const int  slotb = 32 * ((u >> 5) & 1) + 8 * ((u >> 2) & 3) + 4 * ((u >> 4) & 1);
    #pragma unroll
    for (int n = 0; n < 4; ++n) {
      int col = n * 16 + l15;
      float bb = bv[col];
      short4v pk;
      #pragma unroll
      for (int r = 0; r < 4; ++r) pk[r] = (short)f2bf(acc[2][n][r] + bb);
      *reinterpret_cast<short4v*>(ovt + (bidx * Hn + col) * Tn + tb + slotb) = pk;
    }
  }
}

// ---------------------------------------------------------------------------
// Kernel 2: flash attention — 2 KV tiles per barrier period (R29-exact),
// SPLITS=2: grid 512 = exactly 1 round of 2 blocks/CU.  16 tiles/block =
// 8 pairs, 7 barriers.  4 staging buffers (64 KB).
// 2 q-groups/wave, ones-MFMA row-sum, setprio, bf16 O-partials.
// ---------------------------------------------------------------------------
__global__ __launch_bounds__(256, 2) void flash_attn(
    const u16* __restrict__ q, const u16* __restrict__ k,
    const u16* __restrict__ vt, u16* __restrict__ opart,
    float* __restrict__ lpart)
{
  __shared__ u16 kbuf[4][64 * 64];   // 32 KB
  __shared__ u16 vbuf[4][64 * 64];   // 32 KB

  const int t    = threadIdx.x;
  const int lane = t & 63;
  const int w    = t >> 6;
  const int l15  = lane & 15;
  const int lh   = lane >> 4;
  // XCD swizzle (bijective over 512): each XCD gets 64 consecutive ids
  const int swz_id = (blockIdx.x & 7) * 64 + (blockIdx.x >> 3);
  const int b     = swz_id / 32;           // 2 batches per XCD
  const int rem   = swz_id % 32;
  const int split = rem / 16;
  const int qt    = rem % 16;
  const long rowbase = (long)b * Tn + qt * 128;
  const int it0 = split * 16;              // 16 tiles per block

  short8 aq[2][2];
  #pragma unroll
  for (int qg = 0; qg < 2; ++qg) {
    const u16* qrow = q + (rowbase + w * 32 + qg * 16 + l15) * Hn;
    aq[qg][0] = *reinterpret_cast<const short8*>(qrow + lh * 8);
    aq[qg][1] = *reinterpret_cast<const short8*>(qrow + 32 + lh * 8);
  }

  // all-ones A-fragment (bf16 1.0 splat)
  union { short8 s8; uint32_t u[4]; } ON;
  #pragma unroll
  for (int i = 0; i < 4; ++i) ON.u[i] = 0x3F803F80u;

  f32x4 o[2][4];
  #pragma unroll
  for (int qg = 0; qg < 2; ++qg)
    #pragma unroll
    for (int m = 0; m < 4; ++m) o[qg][m] = f32x4{0.f, 0.f, 0.f, 0.f};
  f32x4 ls0 = f32x4{0.f, 0.f, 0.f, 0.f};
  f32x4 ls1 = f32x4{0.f, 0.f, 0.f, 0.f};

  const u16* kb_g = k  + (long)b * Tn * Hn;
  const u16* vb_g = vt + (long)b * Hn * Tn;

  // staging: 16B granule-XOR folded into per-lane GLOBAL source (rule #21)
  const int g0 = t, g1 = 256 + t;
  const int r0g = g0 >> 3, c0g = g0 & 7;
  const int r1g = g1 >> 3, c1g = g1 & 7;
  const long ksrc0 = (long)r0g * Hn + ((c0g ^ (r0g & 7)) << 3);
  const long ksrc1 = (long)r1g * Hn + ((c1g ^ (r1g & 7)) << 3);
  const long vsrc0 = (long)r0g * Tn + ((c0g ^ (r0g & 7)) << 3);
  const long vsrc1 = (long)r1g * Tn + ((c1g ^ (r1g & 7)) << 3);
  const int wb0 = w * 64 * 8;
  const int wb1 = wb0 + 256 * 8;

  // fragment-read swizzle
  const int swz  = l15 & 7;
  const int cks0 = ((0 * 4 + lh) ^ swz) << 3;
  const int cks1 = ((1 * 4 + lh) ^ swz) << 3;
  const int rfr  = l15 * 64;

  // stage one tile (4 gl16) into buffer slot bs
  auto stage = [&](int it, int bs) {
    const u16* kt = kb_g + (long)it * 64 * Hn;
    const u16* vp = vb_g + it * 64;
    gl16(kt + ksrc0, &kbuf[bs][wb0]);
    gl16(kt + ksrc1, &kbuf[bs][wb1]);
    gl16(vp + vsrc0, &vbuf[bs][wb0]);
    gl16(vp + vsrc1, &vbuf[bs][wb1]);
  };

  // compute one tile from buffer slot bs (QK -> exp2 -> PV, accumulating)
  auto tile_compute = [&](int bs) {
    const u16* kc  = &kbuf[bs][0];
    const u16* vcb = &vbuf[bs][0];

    f32x4 s0[4], s1[4];
    #pragma unroll
    for (int n = 0; n < 4; ++n) { s0[n] = f32x4{0.f,0.f,0.f,0.f}; s1[n] = f32x4{0.f,0.f,0.f,0.f}; }
    __builtin_amdgcn_s_setprio(1);
    #pragma unroll
    for (int n = 0; n < 4; ++n) {
      const short8 ak0 = *reinterpret_cast<const short8*>(&kc[n * 1024 + rfr + cks0]);
      const short8 ak1 = *reinterpret_cast<const short8*>(&kc[n * 1024 + rfr + cks1]);
      s0[n] = MFMA16(ak0, aq[0][0], s0[n]);
      s0[n] = MFMA16(ak1, aq[0][1], s0[n]);
      s1[n] = MFMA16(ak0, aq[1][0], s1[n]);
      s1[n] = MFMA16(ak1, aq[1][1], s1[n]);
    }
    __builtin_amdgcn_s_setprio(0);

    #pragma unroll
    for (int n = 0; n < 4; ++n)
      #pragma unroll
      for (int r = 0; r < 4; ++r) {
        s0[n][r] = __builtin_amdgcn_exp2f(s0[n][r]);
        s1[n][r] = __builtin_amdgcn_exp2f(s1[n][r]);
      }

    union { short8 s8; uint32_t u[4]; } B00, B01, B10, B11;
    B00.u[0] = pkbf(s0[0][0], s0[0][1]); B00.u[1] = pkbf(s0[0][2], s0[0][3]);
    B00.u[2] = pkbf(s0[1][0], s0[1][1]); B00.u[3] = pkbf(s0[1][2], s0[1][3]);
    B01.u[0] = pkbf(s0[2][0], s0[2][1]); B01.u[1] = pkbf(s0[2][2], s0[2][3]);
    B01.u[2] = pkbf(s0[3][0], s0[3][1]); B01.u[3] = pkbf(s0[3][2], s0[3][3]);
    B10.u[0] = pkbf(s1[0][0], s1[0][1]); B10.u[1] = pkbf(s1[0][2], s1[0][3]);
    B10.u[2] = pkbf(s1[1][0], s1[1][1]); B10.u[3] = pkbf(s1[1][2], s1[1][3]);
    B11.u[0] = pkbf(s1[2][0], s1[2][1]); B11.u[1] = pkbf(s1[2][2], s1[2][3]);
    B11.u[2] = pkbf(s1[3][0], s1[3][1]); B11.u[3] = pkbf(s1[3][2], s1[3][3]);

    __builtin_amdgcn_s_setprio(1);
    #pragma unroll
    for (int m = 0; m < 4; ++m) {
      const short8 av0 = *reinterpret_cast<const short8*>(&vcb[m * 1024 + rfr + cks0]);
      const short8 av1 = *reinterpret_cast<const short8*>(&vcb[m * 1024 + rfr + cks1]);
      o[0][m] = MFMA16(av0, B00.s8, o[0][m]);
      o[0][m] = MFMA16(av1, B01.s8, o[0][m]);
      o[1][m] = MFMA16(av0, B10.s8, o[1][m]);
      o[1][m] = MFMA16(av1, B11.s8, o[1][m]);
    }
    ls0 = MFMA16(ON.s8, B00.s8, ls0);
    ls0 = MFMA16(ON.s8, B01.s8, ls0);
    ls1 = MFMA16(ON.s8, B10.s8, ls1);
    ls1 = MFMA16(ON.s8, B11.s8, ls1);
    __builtin_amdgcn_s_setprio(0);
  };

  // prologue: stage tiles 0..3 into buffers 0..3 (16 gl16)
  stage(it0 + 0, 0);
  stage(it0 + 1, 1);
  stage(it0 + 2, 2);
  stage(it0 + 3, 3);
  asm volatile("s_waitcnt vmcnt(8)" ::: "memory");   // tiles 0,1 landed
  __builtin_amdgcn_s_barrier();
  __builtin_amdgcn_sched_barrier(0);

  for (int p = 0; p < 8; ++p) {
    const int bA = (2 * p) & 3;
    const int bB = (2 * p + 1) & 3;
    tile_compute(bA);
    tile_compute(bB);

    if (p < 7) {
      asm volatile("s_waitcnt vmcnt(0)" ::: "memory");  // pair p+1 landed
      __builtin_amdgcn_s_barrier();
      __builtin_amdgcn_sched_barrier(0);
      if (p < 6) {
        stage(it0 + 2 * p + 4, bA);   // refill just-freed buffers
        stage(it0 + 2 * p + 5, bB);
      }
    }
  }

  // epilogue: write BF16 unnormalized O-partials + f32 l
  #pragma unroll
  for (int qg = 0; qg < 2; ++qg) {
    const float tot = (qg == 0) ? ls0[0] : ls1[0];
    const long qrow = rowbase + w * 32 + qg * 16 + l15;
    u16* od = opart + ((long)split * NELT) + qrow * Hn;
    #pragma unroll
    for (int m = 0; m < 4; ++m) {
      uint32_t p0 = pkbf(o[qg][m][0], o[qg][m][1]);
      uint32_t p1 = pkbf(o[qg][m][2], o[qg][m][3]);
      uint32_t* dst = reinterpret_cast<uint32_t*>(od + m * 16 + lh * 4);
      dst[0] = p0; dst[1] = p1;
    }
    if (lh == 0) lpart[(long)split * NTOK + qrow] = tot;
  }
}

// ---------------------------------------------------------------------------
// Kernel 3: combine bf16 split-K partials: out = (sum O_s) / (sum l_s)
// 1024 blocks x 256 thr; 8 elems per thread.
// ---------------------------------------------------------------------------
__global__ __launch_bounds__(256) void combine(
    const u16* __restrict__ op, const float* __restrict__ lp,
    float* __restrict__ out)
{
  const long idx  = (long)blockIdx.x * 256 + threadIdx.x;
  const long base = idx * 8;
  const long row  = base >> 6;
  float lsum = 0.f;
  #pragma unroll
  for (int s = 0; s < SPLITS; ++s) lsum += lp[s * NTOK + row];
  const float linv = 1.0f / lsum;

  float acc[8] = {0.f, 0.f, 0.f, 0.f, 0.f, 0.f, 0.f, 0.f};
  #pragma unroll
  for (int s = 0; s < SPLITS; ++s) {
    union { short8 v; u16 u[8]; } pk;
    pk.v = *reinterpret_cast<const short8*>(op + s * NELT + base);
    #pragma unroll
    for (int j = 0; j < 8; ++j) {
      union { uint32_t u; float f; } c; c.u = ((uint32_t)pk.u[j]) << 16;
      acc[j] += c.f;
    }
  }
  float4 r0, r1;
  r0.x = acc[0] * linv; r0.y = acc[1] * linv; r0.z = acc[2] * linv; r0.w = acc[3] * linv;
  r1.x = acc[4] * linv; r1.y = acc[5] * linv; r1.z = acc[6] * linv; r1.w = acc[7] * linv;
  *reinterpret_cast<float4*>(out + base)     = r0;
  *reinterpret_cast<float4*>(out + base + 4) = r1;
}

// ---------------------------------------------------------------------------
extern "C" void kernel_launch(void* const* d_in, const int* in_sizes, int n_in,
                              void* d_out, int out_size, void* d_ws, size_t ws_size,
                              hipStream_t stream) {
  const float* x  = (const float*)d_in[0];
  const float* Wq = (const float*)d_in[1];
  const float* bq = (const float*)d_in[2];
  const float* Wk = (const float*)d_in[3];
  const float* bk = (const float*)d_in[4];
  const float* Wv = (const float*)d_in[5];
  const float* bv = (const float*)d_in[6];
  float* out = (float*)d_out;

  u16* qs  = (u16*)d_ws;                         // [32768][64] bf16, pre-scaled
  u16* ks  = qs + NELT;                          // [32768][64] bf16
  u16* vs  = ks + NELT;                          // V^T [16][64][2048] bf16 (PI-slot order)
  u16* wtd = vs + NELT;                          // WT [3][64][384] bf16
  u16* op  = wtd + 3 * 64 * Cn;                  // O partials [SPLITS][32768][64] bf16
  float* lp = (float*)(op + (long)SPLITS * NELT);// l partials [SPLITS][32768] f32

  hipLaunchKernelGGL(wtrans, dim3(18), dim3(256), 0, stream, Wq, Wk, Wv, wtd);
  hipLaunchKernelGGL(qkv_proj, dim3((int)(NTOK / 64)), dim3(256), 0, stream,
                     x, wtd, bq, bk, bv, qs, ks, vs);
  hipLaunchKernelGGL(flash_attn, dim3(16 * 16 * SPLITS), dim3(256), 0, stream,
                     qs, ks, vs, op, lp);
  hipLaunchKernelGGL(combine, dim3((int)(NELT / 8 / 256)), dim3(256), 0, stream,
                     op, lp, out);
}

// Round 37
// 50.239 us; speedup vs baseline: 1.0033x; 1.0033x over previous
//
#include <hip/hip_runtime.h>
#include <hip/hip_bf16.h>
#include <cstdint>

typedef unsigned short u16;
typedef __attribute__((ext_vector_type(8))) short short8;   // 8 bf16 = 4 VGPR
typedef __attribute__((ext_vector_type(4))) short short4v;  // 4 bf16 = 8B
typedef __attribute__((ext_vector_type(4))) float f32x4;

#define MFMA16(a, b, c) __builtin_amdgcn_mfma_f32_16x16x32_bf16((a), (b), (c), 0, 0, 0)

constexpr int Bn   = 16;
constexpr int Tn   = 2048;
constexpr int Cn   = 384;
constexpr int Hn   = 64;
constexpr long NTOK = (long)Bn * Tn;          // 32768
constexpr long NELT = NTOK * Hn;              // 2,097,152
constexpr int SPLITS = 2;                     // grid 512 = 1 round of 2 blocks/CU

// Q pre-scale: (1/sqrt(64)) * log2(e), so attention uses bare exp2
#define QSCALE 0.18033688011112042f

// f32 -> bf16 round-to-nearest-even
__device__ __forceinline__ u16 f2bf(float f) {
  union { float f; uint32_t u; } c; c.f = f;
  uint32_t u = c.u;
  return (u16)((u + 0x7fffu + ((u >> 16) & 1u)) >> 16);
}

// pack 2 f32 -> 2 bf16 in one u32 (RNE), gfx950 v_cvt_pk_bf16_f32
__device__ __forceinline__ uint32_t pkbf(float a, float b) {
  uint32_t d;
  asm("v_cvt_pk_bf16_f32 %0, %1, %2" : "=v"(d) : "v"(a), "v"(b));
  return d;
}

// load 8 consecutive f32 and pack to one bf16x8 A-fragment word
__device__ __forceinline__ short8 ldx8(const float* p) {
  const float4 f0 = *reinterpret_cast<const float4*>(p);
  const float4 f1 = *reinterpret_cast<const float4*>(p + 4);
  union { short8 s8; uint32_t u[4]; } r;
  r.u[0] = pkbf(f0.x, f0.y); r.u[1] = pkbf(f0.z, f0.w);
  r.u[2] = pkbf(f1.x, f1.y); r.u[3] = pkbf(f1.z, f1.w);
  return r.s8;
}

// async global->LDS, 16B per lane. LDS dest = wave-uniform base + lane*16.
__device__ __forceinline__ void gl16(const u16* g, const u16* l) {
  __builtin_amdgcn_global_load_lds(
      (const __attribute__((address_space(1))) void*)g,
      (__attribute__((address_space(3))) void*)l, 16, 0, 0);
}

// ---------------------------------------------------------------------------
// Kernel 0: W pre-transpose.  W[384][64] f32 (x3) -> WT[3][64][384] bf16.
// ---------------------------------------------------------------------------
__global__ __launch_bounds__(256) void wtrans(
    const float* __restrict__ Wq, const float* __restrict__ Wk,
    const float* __restrict__ Wv, u16* __restrict__ wtd)
{
  __shared__ u16 tile[64][65];
  const int m  = blockIdx.x / 6;
  const int kc = blockIdx.x % 6;
  const float* W = (m == 0) ? Wq : (m == 1) ? Wk : Wv;
  const int t = threadIdx.x;

  {
    const int kr = t >> 2, seg = t & 3;
    const float* src = W + (size_t)(kc * 64 + kr) * Hn + seg * 16;
    #pragma unroll
    for (int j = 0; j < 4; ++j) {
      const float4 f = *reinterpret_cast<const float4*>(src + j * 4);
      u16* p = &tile[kr][seg * 16 + j * 4];
      p[0] = f2bf(f.x); p[1] = f2bf(f.y); p[2] = f2bf(f.z); p[3] = f2bf(f.w);
    }
  }
  __syncthreads();
  {
    const int hr = t >> 2, seg = t & 3;
    union { short8 s; u16 u[8]; } o0, o1;
    #pragma unroll
    for (int j = 0; j < 8; ++j) o0.u[j] = tile[seg * 16 + j][hr];
    #pragma unroll
    for (int j = 0; j < 8; ++j) o1.u[j] = tile[seg * 16 + 8 + j][hr];
    u16* dst = wtd + ((size_t)m * 64 + hr) * Cn + kc * 64 + seg * 16;
    *reinterpret_cast<short8*>(dst)     = o0.s;
    *reinterpret_cast<short8*>(dst + 8) = o1.s;
  }
}

// ---------------------------------------------------------------------------
// Kernel 1: QKV projection: triple-buffered W gl16 + 2-deep x prefetch,
// counted vmcnt chain.  Grid 512 x 256; LDS 72 KB.
// ---------------------------------------------------------------------------
__global__ __launch_bounds__(256, 2) void qkv_proj(
    const float* __restrict__ x, const u16* __restrict__ wtd,
    const float* __restrict__ bq, const float* __restrict__ bk,
    const float* __restrict__ bv,
    u16* __restrict__ oq, u16* __restrict__ ok, u16* __restrict__ ovt)
{
  __shared__ u16 wbuf[3][3 * 64 * 64];   // 3 x 24 KB, swizzled granules

  const int t    = threadIdx.x;
  const int lane = t & 63;
  const int w    = t >> 6;
  const int l15  = lane & 15;
  const int lh   = lane >> 4;
  const long r0  = (long)blockIdx.x * 64;

  int srcoff[6];
  #pragma unroll
  for (int i = 0; i < 6; ++i) {
    const int g = i * 256 + t;
    const int r = g >> 3, c = g & 7;
    srcoff[i] = r * Cn + ((c ^ (r & 7)) << 3);
  }
  const int ldsb = w * 64 * 8;

  const float* xrow = x + (r0 + w * 16 + l15) * Cn;

  const int cks0 = ((lh)     ^ (l15 & 7)) << 3;
  const int cks1 = ((lh + 4) ^ (l15 & 7)) << 3;

  f32x4 acc[3][4];
  #pragma unroll
  for (int m = 0; m < 3; ++m)
    #pragma unroll
    for (int n = 0; n < 4; ++n) acc[m][n] = f32x4{0.f, 0.f, 0.f, 0.f};

  #pragma unroll
  for (int i = 0; i < 6; ++i)
    gl16(wtd + srcoff[i], &wbuf[0][(i * 256) * 8 + ldsb]);
  short8 aCur0 = ldx8(xrow + lh * 8);
  short8 aCur1 = ldx8(xrow + 32 + lh * 8);
  #pragma unroll
  for (int i = 0; i < 6; ++i)
    gl16(wtd + 64 + srcoff[i], &wbuf[1][(i * 256) * 8 + ldsb]);
  short8 aNx10 = ldx8(xrow + 64 + lh * 8);
  short8 aNx11 = ldx8(xrow + 96 + lh * 8);
  short8 aNx20, aNx21;
  asm volatile("s_waitcnt vmcnt(14)" ::: "memory");
  __builtin_amdgcn_s_barrier();
  __builtin_amdgcn_sched_barrier(0);

  for (int kc = 0; kc < 6; ++kc) {
    const int cb = kc % 3;
    const int sb = (kc + 2) % 3;
    if (kc + 2 < 6) {
      #pragma unroll
      for (int i = 0; i < 6; ++i)
        gl16(wtd + (kc + 2) * 64 + srcoff[i], &wbuf[sb][(i * 256) * 8 + ldsb]);
      const float* p = xrow + (kc + 2) * 64 + lh * 8;
      aNx20 = ldx8(p);
      aNx21 = ldx8(p + 32);
    }

    const u16* wc = &wbuf[cb][0];
    #pragma unroll
    for (int m = 0; m < 3; ++m)
      #pragma unroll
      for (int n = 0; n < 4; ++n) {
        const int row = m * 64 + n * 16 + l15;
        const short8 b0 = *reinterpret_cast<const short8*>(&wc[row * 64 + cks0]);
        acc[m][n] = MFMA16(aCur0, b0, acc[m][n]);
        const short8 b1 = *reinterpret_cast<const short8*>(&wc[row * 64 + cks1]);
        acc[m][n] = MFMA16(aCur1, b1, acc[m][n]);
      }

    if (kc + 1 < 6) {
      if (kc + 2 < 6) asm volatile("s_waitcnt vmcnt(14)" ::: "memory");
      else            asm volatile("s_waitcnt vmcnt(4)"  ::: "memory");
      __builtin_amdgcn_s_barrier();
      __builtin_amdgcn_sched_barrier(0);
      aCur0 = aNx10; aCur1 = aNx11;
      aNx10 = aNx20; aNx11 = aNx21;
    }
  }

  {
    const float* bias[2] = {bq, bk};
    u16*         dst[2]  = {oq, ok};
    const float  scl[2]  = {QSCALE, 1.0f};
    #pragma unroll
    for (int m = 0; m < 2; ++m) {
      #pragma unroll
      for (int n = 0; n < 4; ++n) {
        int col = n * 16 + l15;
        float bb = bias[m][col];
        #pragma unroll
        for (int r = 0; r < 4; ++r) {
          int row = lh * 4 + r;
          dst[m][(r0 + w * 16 + row) * Hn + col] = f2bf((acc[m][n][r] + bb) * scl[m]);
        }
      }
    }
  }
  {
    const long g    = r0 + w * 16 + lh * 4;
    const long bidx = g >> 11;
    const long tloc = g & 2047;
    const int  u    = (int)(tloc & 63);
    const long tb   = tloc & ~63L;
    const int  slotb = 32 * ((u >> 5) & 1) + 8 * ((u >> 2) & 3) + 4 * ((u >> 4) & 1);
    #pragma unroll
    for (int n = 0; n < 4; ++n) {
      int col = n * 16 + l15;
      float bb = bv[col];
      short4v pk;
      #pragma unroll
      for (int r = 0; r < 4; ++r) pk[r] = (short)f2bf(acc[2][n][r] + bb);
      *reinterpret_cast<short4v*>(ovt + (bidx * Hn + col) * Tn + tb + slotb) = pk;
    }
  }
}

// ---------------------------------------------------------------------------
// Kernel 2: flash attention — 2 KV tiles per barrier period (R29-exact),
// SPLITS=2: grid 512 = exactly 1 round of 2 blocks/CU.  16 tiles/block =
// 8 pairs, 7 barriers.  4 staging buffers (64 KB).
// 2 q-groups/wave, ones-MFMA row-sum, setprio, bf16 O-partials.
// ---------------------------------------------------------------------------
__global__ __launch_bounds__(256, 2) void flash_attn(
    const u16* __restrict__ q, const u16* __restrict__ k,
    const u16* __restrict__ vt, u16* __restrict__ opart,
    float* __restrict__ lpart)
{
  __shared__ u16 kbuf[4][64 * 64];   // 32 KB
  __shared__ u16 vbuf[4][64 * 64];   // 32 KB

  const int t    = threadIdx.x;
  const int lane = t & 63;
  const int w    = t >> 6;
  const int l15  = lane & 15;
  const int lh   = lane >> 4;
  // XCD swizzle (bijective over 512): each XCD gets 64 consecutive ids
  const int swz_id = (blockIdx.x & 7) * 64 + (blockIdx.x >> 3);
  const int b     = swz_id / 32;           // 2 batches per XCD
  const int rem   = swz_id % 32;
  const int split = rem / 16;
  const int qt    = rem % 16;
  const long rowbase = (long)b * Tn + qt * 128;
  const int it0 = split * 16;              // 16 tiles per block

  short8 aq[2][2];
  #pragma unroll
  for (int qg = 0; qg < 2; ++qg) {
    const u16* qrow = q + (rowbase + w * 32 + qg * 16 + l15) * Hn;
    aq[qg][0] = *reinterpret_cast<const short8*>(qrow + lh * 8);
    aq[qg][1] = *reinterpret_cast<const short8*>(qrow + 32 + lh * 8);
  }

  // all-ones A-fragment (bf16 1.0 splat)
  union { short8 s8; uint32_t u[4]; } ON;
  #pragma unroll
  for (int i = 0; i < 4; ++i) ON.u[i] = 0x3F803F80u;

  f32x4 o[2][4];
  #pragma unroll
  for (int qg = 0; qg < 2; ++qg)
    #pragma unroll
    for (int m = 0; m < 4; ++m) o[qg][m] = f32x4{0.f, 0.f, 0.f, 0.f};
  f32x4 ls0 = f32x4{0.f, 0.f, 0.f, 0.f};
  f32x4 ls1 = f32x4{0.f, 0.f, 0.f, 0.f};

  const u16* kb_g = k  + (long)b * Tn * Hn;
  const u16* vb_g = vt + (long)b * Hn * Tn;

  // staging: 16B granule-XOR folded into per-lane GLOBAL source (rule #21)
  const int g0 = t, g1 = 256 + t;
  const int r0g = g0 >> 3, c0g = g0 & 7;
  const int r1g = g1 >> 3, c1g = g1 & 7;
  const long ksrc0 = (long)r0g * Hn + ((c0g ^ (r0g & 7)) << 3);
  const long ksrc1 = (long)r1g * Hn + ((c1g ^ (r1g & 7)) << 3);
  const long vsrc0 = (long)r0g * Tn + ((c0g ^ (r0g & 7)) << 3);
  const long vsrc1 = (long)r1g * Tn + ((c1g ^ (r1g & 7)) << 3);
  const int wb0 = w * 64 * 8;
  const int wb1 = wb0 + 256 * 8;

  // fragment-read swizzle
  const int swz  = l15 & 7;
  const int cks0 = ((0 * 4 + lh) ^ swz) << 3;
  const int cks1 = ((1 * 4 + lh) ^ swz) << 3;
  const int rfr  = l15 * 64;

  // stage one tile (4 gl16) into buffer slot bs
  auto stage = [&](int it, int bs) {
    const u16* kt = kb_g + (long)it * 64 * Hn;
    const u16* vp = vb_g + it * 64;
    gl16(kt + ksrc0, &kbuf[bs][wb0]);
    gl16(kt + ksrc1, &kbuf[bs][wb1]);
    gl16(vp + vsrc0, &vbuf[bs][wb0]);
    gl16(vp + vsrc1, &vbuf[bs][wb1]);
  };

  // compute one tile from buffer slot bs (QK -> exp2 -> PV, accumulating)
  auto tile_compute = [&](int bs) {
    const u16* kc  = &kbuf[bs][0];
    const u16* vcb = &vbuf[bs][0];

    f32x4 s0[4], s1[4];
    #pragma unroll
    for (int n = 0; n < 4; ++n) { s0[n] = f32x4{0.f,0.f,0.f,0.f}; s1[n] = f32x4{0.f,0.f,0.f,0.f}; }
    __builtin_amdgcn_s_setprio(1);
    #pragma unroll
    for (int n = 0; n < 4; ++n) {
      const short8 ak0 = *reinterpret_cast<const short8*>(&kc[n * 1024 + rfr + cks0]);
      const short8 ak1 = *reinterpret_cast<const short8*>(&kc[n * 1024 + rfr + cks1]);
      s0[n] = MFMA16(ak0, aq[0][0], s0[n]);
      s0[n] = MFMA16(ak1, aq[0][1], s0[n]);
      s1[n] = MFMA16(ak0, aq[1][0], s1[n]);
      s1[n] = MFMA16(ak1, aq[1][1], s1[n]);
    }
    __builtin_amdgcn_s_setprio(0);

    #pragma unroll
    for (int n = 0; n < 4; ++n)
      #pragma unroll
      for (int r = 0; r < 4; ++r) {
        s0[n][r] = __builtin_amdgcn_exp2f(s0[n][r]);
        s1[n][r] = __builtin_amdgcn_exp2f(s1[n][r]);
      }

    union { short8 s8; uint32_t u[4]; } B00, B01, B10, B11;
    B00.u[0] = pkbf(s0[0][0], s0[0][1]); B00.u[1] = pkbf(s0[0][2], s0[0][3]);
    B00.u[2] = pkbf(s0[1][0], s0[1][1]); B00.u[3] = pkbf(s0[1][2], s0[1][3]);
    B01.u[0] = pkbf(s0[2][0], s0[2][1]); B01.u[1] = pkbf(s0[2][2], s0[2][3]);
    B01.u[2] = pkbf(s0[3][0], s0[3][1]); B01.u[3] = pkbf(s0[3][2], s0[3][3]);
    B10.u[0] = pkbf(s1[0][0], s1[0][1]); B10.u[1] = pkbf(s1[0][2], s1[0][3]);
    B10.u[2] = pkbf(s1[1][0], s1[1][1]); B10.u[3] = pkbf(s1[1][2], s1[1][3]);
    B11.u[0] = pkbf(s1[2][0], s1[2][1]); B11.u[1] = pkbf(s1[2][2], s1[2][3]);
    B11.u[2] = pkbf(s1[3][0], s1[3][1]); B11.u[3] = pkbf(s1[3][2], s1[3][3]);

    __builtin_amdgcn_s_setprio(1);
    #pragma unroll
    for (int m = 0; m < 4; ++m) {
      const short8 av0 = *reinterpret_cast<const short8*>(&vcb[m * 1024 + rfr + cks0]);
      const short8 av1 = *reinterpret_cast<const short8*>(&vcb[m * 1024 + rfr + cks1]);
      o[0][m] = MFMA16(av0, B00.s8, o[0][m]);
      o[0][m] = MFMA16(av1, B01.s8, o[0][m]);
      o[1][m] = MFMA16(av0, B10.s8, o[1][m]);
      o[1][m] = MFMA16(av1, B11.s8, o[1][m]);
    }
    ls0 = MFMA16(ON.s8, B00.s8, ls0);
    ls0 = MFMA16(ON.s8, B01.s8, ls0);
    ls1 = MFMA16(ON.s8, B10.s8, ls1);
    ls1 = MFMA16(ON.s8, B11.s8, ls1);
    __builtin_amdgcn_s_setprio(0);
  };

  // prologue: stage tiles 0..3 into buffers 0..3 (16 gl16)
  stage(it0 + 0, 0);
  stage(it0 + 1, 1);
  stage(it0 + 2, 2);
  stage(it0 + 3, 3);
  asm volatile("s_waitcnt vmcnt(8)" ::: "memory");   // tiles 0,1 landed
  __builtin_amdgcn_s_barrier();
  __builtin_amdgcn_sched_barrier(0);

  for (int p = 0; p < 8; ++p) {
    const int bA = (2 * p) & 3;
    const int bB = (2 * p + 1) & 3;
    tile_compute(bA);
    tile_compute(bB);

    if (p < 7) {
      asm volatile("s_waitcnt vmcnt(0)" ::: "memory");  // pair p+1 landed
      __builtin_amdgcn_s_barrier();
      __builtin_amdgcn_sched_barrier(0);
      if (p < 6) {
        stage(it0 + 2 * p + 4, bA);   // refill just-freed buffers
        stage(it0 + 2 * p + 5, bB);
      }
    }
  }

  // epilogue: write BF16 unnormalized O-partials + f32 l
  #pragma unroll
  for (int qg = 0; qg < 2; ++qg) {
    const float tot = (qg == 0) ? ls0[0] : ls1[0];
    const long qrow = rowbase + w * 32 + qg * 16 + l15;
    u16* od = opart + ((long)split * NELT) + qrow * Hn;
    #pragma unroll
    for (int m = 0; m < 4; ++m) {
      uint32_t p0 = pkbf(o[qg][m][0], o[qg][m][1]);
      uint32_t p1 = pkbf(o[qg][m][2], o[qg][m][3]);
      uint32_t* dst = reinterpret_cast<uint32_t*>(od + m * 16 + lh * 4);
      dst[0] = p0; dst[1] = p1;
    }
    if (lh == 0) lpart[(long)split * NTOK + qrow] = tot;
  }
}

// ---------------------------------------------------------------------------
// Kernel 3: combine bf16 split-K partials: out = (sum O_s) / (sum l_s)
// 1024 blocks x 256 thr; 8 elems per thread.
// ---------------------------------------------------------------------------
__global__ __launch_bounds__(256) void combine(
    const u16* __restrict__ op, const float* __restrict__ lp,
    float* __restrict__ out)
{
  const long idx  = (long)blockIdx.x * 256 + threadIdx.x;
  const long base = idx * 8;
  const long row  = base >> 6;
  float lsum = 0.f;
  #pragma unroll
  for (int s = 0; s < SPLITS; ++s) lsum += lp[s * NTOK + row];
  const float linv = 1.0f / lsum;

  float acc[8] = {0.f, 0.f, 0.f, 0.f, 0.f, 0.f, 0.f, 0.f};
  #pragma unroll
  for (int s = 0; s < SPLITS; ++s) {
    union { short8 v; u16 u[8]; } pk;
    pk.v = *reinterpret_cast<const short8*>(op + s * NELT + base);
    #pragma unroll
    for (int j = 0; j < 8; ++j) {
      union { uint32_t u; float f; } c; c.u = ((uint32_t)pk.u[j]) << 16;
      acc[j] += c.f;
    }
  }
  float4 r0, r1;
  r0.x = acc[0] * linv; r0.y = acc[1] * linv; r0.z = acc[2] * linv; r0.w = acc[3] * linv;
  r1.x = acc[4] * linv; r1.y = acc[5] * linv; r1.z = acc[6] * linv; r1.w = acc[7] * linv;
  *reinterpret_cast<float4*>(out + base)     = r0;
  *reinterpret_cast<float4*>(out + base + 4) = r1;
}

// ---------------------------------------------------------------------------
extern "C" void kernel_launch(void* const* d_in, const int* in_sizes, int n_in,
                              void* d_out, int out_size, void* d_ws, size_t ws_size,
                              hipStream_t stream) {
  const float* x  = (const float*)d_in[0];
  const float* Wq = (const float*)d_in[1];
  const float* bq = (const float*)d_in[2];
  const float* Wk = (const float*)d_in[3];
  const float* bk = (const float*)d_in[4];
  const float* Wv = (const float*)d_in[5];
  const float* bv = (const float*)d_in[6];
  float* out = (float*)d_out;

  u16* qs  = (u16*)d_ws;                         // [32768][64] bf16, pre-scaled
  u16* ks  = qs + NELT;                          // [32768][64] bf16
  u16* vs  = ks + NELT;                          // V^T [16][64][2048] bf16 (PI-slot order)
  u16* wtd = vs + NELT;                          // WT [3][64][384] bf16
  u16* op  = wtd + 3 * 64 * Cn;                  // O partials [SPLITS][32768][64] bf16
  float* lp = (float*)(op + (long)SPLITS * NELT);// l partials [SPLITS][32768] f32

  hipLaunchKernelGGL(wtrans, dim3(18), dim3(256), 0, stream, Wq, Wk, Wv, wtd);
  hipLaunchKernelGGL(qkv_proj, dim3((int)(NTOK / 64)), dim3(256), 0, stream,
                     x, wtd, bq, bk, bv, qs, ks, vs);
  hipLaunchKernelGGL(flash_attn, dim3(16 * 16 * SPLITS), dim3(256), 0, stream,
                     qs, ks, vs, op, lp);
  hipLaunchKernelGGL(combine, dim3((int)(NELT / 8 / 256)), dim3(256), 0, stream,
                     op, lp, out);
}

// Round 38
// 49.937 us; speedup vs baseline: 1.0094x; 1.0060x over previous
//
#include <hip/hip_runtime.h>
#include <hip/hip_bf16.h>
#include <cstdint>

typedef unsigned short u16;
typedef __attribute__((ext_vector_type(8))) short short8;   // 8 bf16 = 4 VGPR
typedef __attribute__((ext_vector_type(4))) short short4v;  // 4 bf16 = 8B
typedef __attribute__((ext_vector_type(4))) float f32x4;

#define MFMA16(a, b, c) __builtin_amdgcn_mfma_f32_16x16x32_bf16((a), (b), (c), 0, 0, 0)

constexpr int Bn   = 16;
constexpr int Tn   = 2048;
constexpr int Cn   = 384;
constexpr int Hn   = 64;
constexpr long NTOK = (long)Bn * Tn;          // 32768
constexpr long NELT = NTOK * Hn;              // 2,097,152
constexpr int SPLITS = 2;                     // grid 512 = 1 round of 2 blocks/CU

// Q pre-scale: (1/sqrt(64)) * log2(e), so attention uses bare exp2
#define QSCALE 0.18033688011112042f

// f32 -> bf16 round-to-nearest-even
__device__ __forceinline__ u16 f2bf(float f) {
  union { float f; uint32_t u; } c; c.f = f;
  uint32_t u = c.u;
  return (u16)((u + 0x7fffu + ((u >> 16) & 1u)) >> 16);
}

// pack 2 f32 -> 2 bf16 in one u32 (RNE), gfx950 v_cvt_pk_bf16_f32
__device__ __forceinline__ uint32_t pkbf(float a, float b) {
  uint32_t d;
  asm("v_cvt_pk_bf16_f32 %0, %1, %2" : "=v"(d) : "v"(a), "v"(b));
  return d;
}

// load 8 consecutive f32 and pack to one bf16x8 A-fragment word
__device__ __forceinline__ short8 ldx8(const float* p) {
  const float4 f0 = *reinterpret_cast<const float4*>(p);
  const float4 f1 = *reinterpret_cast<const float4*>(p + 4);
  union { short8 s8; uint32_t u[4]; } r;
  r.u[0] = pkbf(f0.x, f0.y); r.u[1] = pkbf(f0.z, f0.w);
  r.u[2] = pkbf(f1.x, f1.y); r.u[3] = pkbf(f1.z, f1.w);
  return r.s8;
}

// async global->LDS, 16B per lane. LDS dest = wave-uniform base + lane*16.
__device__ __forceinline__ void gl16(const u16* g, const u16* l) {
  __builtin_amdgcn_global_load_lds(
      (const __attribute__((address_space(1))) void*)g,
      (__attribute__((address_space(3))) void*)l, 16, 0, 0);
}

// ---------------------------------------------------------------------------
// Kernel 0: W pre-transpose.  W[384][64] f32 (x3) -> WT[3][64][384] bf16.
// ---------------------------------------------------------------------------
__global__ __launch_bounds__(256) void wtrans(
    const float* __restrict__ Wq, const float* __restrict__ Wk,
    const float* __restrict__ Wv, u16* __restrict__ wtd)
{
  __shared__ u16 tile[64][65];
  const int m  = blockIdx.x / 6;
  const int kc = blockIdx.x % 6;
  const float* W = (m == 0) ? Wq : (m == 1) ? Wk : Wv;
  const int t = threadIdx.x;

  {
    const int kr = t >> 2, seg = t & 3;
    const float* src = W + (size_t)(kc * 64 + kr) * Hn + seg * 16;
    #pragma unroll
    for (int j = 0; j < 4; ++j) {
      const float4 f = *reinterpret_cast<const float4*>(src + j * 4);
      u16* p = &tile[kr][seg * 16 + j * 4];
      p[0] = f2bf(f.x); p[1] = f2bf(f.y); p[2] = f2bf(f.z); p[3] = f2bf(f.w);
    }
  }
  __syncthreads();
  {
    const int hr = t >> 2, seg = t & 3;
    union { short8 s; u16 u[8]; } o0, o1;
    #pragma unroll
    for (int j = 0; j < 8; ++j) o0.u[j] = tile[seg * 16 + j][hr];
    #pragma unroll
    for (int j = 0; j < 8; ++j) o1.u[j] = tile[seg * 16 + 8 + j][hr];
    u16* dst = wtd + ((size_t)m * 64 + hr) * Cn + kc * 64 + seg * 16;
    *reinterpret_cast<short8*>(dst)     = o0.s;
    *reinterpret_cast<short8*>(dst + 8) = o1.s;
  }
}

// ---------------------------------------------------------------------------
// Kernel 1: QKV projection: triple-buffered W gl16 + 2-deep x prefetch,
// counted vmcnt chain.  Grid 512 x 256; LDS 72 KB.
// ---------------------------------------------------------------------------
__global__ __launch_bounds__(256, 2) void qkv_proj(
    const float* __restrict__ x, const u16* __restrict__ wtd,
    const float* __restrict__ bq, const float* __restrict__ bk,
    const float* __restrict__ bv,
    u16* __restrict__ oq, u16* __restrict__ ok, u16* __restrict__ ovt)
{
  __shared__ u16 wbuf[3][3 * 64 * 64];   // 3 x 24 KB, swizzled granules

  const int t    = threadIdx.x;
  const int lane = t & 63;
  const int w    = t >> 6;
  const int l15  = lane & 15;
  const int lh   = lane >> 4;
  const long r0  = (long)blockIdx.x * 64;

  int srcoff[6];
  #pragma unroll
  for (int i = 0; i < 6; ++i) {
    const int g = i * 256 + t;
    const int r = g >> 3, c = g & 7;
    srcoff[i] = r * Cn + ((c ^ (r & 7)) << 3);
  }
  const int ldsb = w * 64 * 8;

  const float* xrow = x + (r0 + w * 16 + l15) * Cn;

  const int cks0 = ((lh)     ^ (l15 & 7)) << 3;
  const int cks1 = ((lh + 4) ^ (l15 & 7)) << 3;

  f32x4 acc[3][4];
  #pragma unroll
  for (int m = 0; m < 3; ++m)
    #pragma unroll
    for (int n = 0; n < 4; ++n) acc[m][n] = f32x4{0.f, 0.f, 0.f, 0.f};

  #pragma unroll
  for (int i = 0; i < 6; ++i)
    gl16(wtd + srcoff[i], &wbuf[0][(i * 256) * 8 + ldsb]);
  short8 aCur0 = ldx8(xrow + lh * 8);
  short8 aCur1 = ldx8(xrow + 32 + lh * 8);
  #pragma unroll
  for (int i = 0; i < 6; ++i)
    gl16(wtd + 64 + srcoff[i], &wbuf[1][(i * 256) * 8 + ldsb]);
  short8 aNx10 = ldx8(xrow + 64 + lh * 8);
  short8 aNx11 = ldx8(xrow + 96 + lh * 8);
  short8 aNx20, aNx21;
  asm volatile("s_waitcnt vmcnt(14)" ::: "memory");
  __builtin_amdgcn_s_barrier();
  __builtin_amdgcn_sched_barrier(0);

  for (int kc = 0; kc < 6; ++kc) {
    const int cb = kc % 3;
    const int sb = (kc + 2) % 3;
    if (kc + 2 < 6) {
      #pragma unroll
      for (int i = 0; i < 6; ++i)
        gl16(wtd + (kc + 2) * 64 + srcoff[i], &wbuf[sb][(i * 256) * 8 + ldsb]);
      const float* p = xrow + (kc + 2) * 64 + lh * 8;
      aNx20 = ldx8(p);
      aNx21 = ldx8(p + 32);
    }

    const u16* wc = &wbuf[cb][0];
    #pragma unroll
    for (int m = 0; m < 3; ++m)
      #pragma unroll
      for (int n = 0; n < 4; ++n) {
        const int row = m * 64 + n * 16 + l15;
        const short8 b0 = *reinterpret_cast<const short8*>(&wc[row * 64 + cks0]);
        acc[m][n] = MFMA16(aCur0, b0, acc[m][n]);
        const short8 b1 = *reinterpret_cast<const short8*>(&wc[row * 64 + cks1]);
        acc[m][n] = MFMA16(aCur1, b1, acc[m][n]);
      }

    if (kc + 1 < 6) {
      if (kc + 2 < 6) asm volatile("s_waitcnt vmcnt(14)" ::: "memory");
      else            asm volatile("s_waitcnt vmcnt(4)"  ::: "memory");
      __builtin_amdgcn_s_barrier();
      __builtin_amdgcn_sched_barrier(0);
      aCur0 = aNx10; aCur1 = aNx11;
      aNx10 = aNx20; aNx11 = aNx21;
    }
  }

  {
    const float* bias[2] = {bq, bk};
    u16*         dst[2]  = {oq, ok};
    const float  scl[2]  = {QSCALE, 1.0f};
    #pragma unroll
    for (int m = 0; m < 2; ++m) {
      #pragma unroll
      for (int n = 0; n < 4; ++n) {
        int col = n * 16 + l15;
        float bb = bias[m][col];
        #pragma unroll
        for (int r = 0; r < 4; ++r) {
          int row = lh * 4 + r;
          dst[m][(r0 + w * 16 + row) * Hn + col] = f2bf((acc[m][n][r] + bb) * scl[m]);
        }
      }
    }
  }
  {
    const long g    = r0 + w * 16 + lh * 4;
    const long bidx = g >> 11;
    const long tloc = g & 2047;
    const int  u    = (int)(tloc & 63);
    const long tb   = tloc & ~63L;
    const int  slotb = 32 * ((u >> 5) & 1) + 8 * ((u >> 2) & 3) + 4 * ((u >> 4) & 1);
    #pragma unroll
    for (int n = 0; n < 4; ++n) {
      int col = n * 16 + l15;
      float bb = bv[col];
      short4v pk;
      #pragma unroll
      for (int r = 0; r < 4; ++r) pk[r] = (short)f2bf(acc[2][n][r] + bb);
      *reinterpret_cast<short4v*>(ovt + (bidx * Hn + col) * Tn + tb + slotb) = pk;
    }
  }
}

// ---------------------------------------------------------------------------
// Kernel 2: flash attention — 2 KV tiles per barrier period (R29-exact),
// SPLITS=2: grid 512 = exactly 1 round of 2 blocks/CU.  16 tiles/block =
// 8 pairs, 7 barriers.  4 staging buffers (64 KB).
// 2 q-groups/wave, ones-MFMA row-sum, setprio, bf16 O-partials.
// ---------------------------------------------------------------------------
__global__ __launch_bounds__(256, 2) void flash_attn(
    const u16* __restrict__ q, const u16* __restrict__ k,
    const u16* __restrict__ vt, u16* __restrict__ opart,
    float* __restrict__ lpart)
{
  __shared__ u16 kbuf[4][64 * 64];   // 32 KB
  __shared__ u16 vbuf[4][64 * 64];   // 32 KB

  const int t    = threadIdx.x;
  const int lane = t & 63;
  const int w    = t >> 6;
  const int l15  = lane & 15;
  const int lh   = lane >> 4;
  // XCD swizzle (bijective over 512): each XCD gets 64 consecutive ids
  const int swz_id = (blockIdx.x & 7) * 64 + (blockIdx.x >> 3);
  const int b     = swz_id / 32;           // 2 batches per XCD
  const int rem   = swz_id % 32;
  const int split = rem / 16;
  const int qt    = rem % 16;
  const long rowbase = (long)b * Tn + qt * 128;
  const int it0 = split * 16;              // 16 tiles per block

  short8 aq[2][2];
  #pragma unroll
  for (int qg = 0; qg < 2; ++qg) {
    const u16* qrow = q + (rowbase + w * 32 + qg * 16 + l15) * Hn;
    aq[qg][0] = *reinterpret_cast<const short8*>(qrow + lh * 8);
    aq[qg][1] = *reinterpret_cast<const short8*>(qrow + 32 + lh * 8);
  }

  // all-ones A-fragment (bf16 1.0 splat)
  union { short8 s8; uint32_t u[4]; } ON;
  #pragma unroll
  for (int i = 0; i < 4; ++i) ON.u[i] = 0x3F803F80u;

  f32x4 o[2][4];
  #pragma unroll
  for (int qg = 0; qg < 2; ++qg)
    #pragma unroll
    for (int m = 0; m < 4; ++m) o[qg][m] = f32x4{0.f, 0.f, 0.f, 0.f};
  f32x4 ls0 = f32x4{0.f, 0.f, 0.f, 0.f};
  f32x4 ls1 = f32x4{0.f, 0.f, 0.f, 0.f};

  const u16* kb_g = k  + (long)b * Tn * Hn;
  const u16* vb_g = vt + (long)b * Hn * Tn;

  // staging: 16B granule-XOR folded into per-lane GLOBAL source (rule #21)
  const int g0 = t, g1 = 256 + t;
  const int r0g = g0 >> 3, c0g = g0 & 7;
  const int r1g = g1 >> 3, c1g = g1 & 7;
  const long ksrc0 = (long)r0g * Hn + ((c0g ^ (r0g & 7)) << 3);
  const long ksrc1 = (long)r1g * Hn + ((c1g ^ (r1g & 7)) << 3);
  const long vsrc0 = (long)r0g * Tn + ((c0g ^ (r0g & 7)) << 3);
  const long vsrc1 = (long)r1g * Tn + ((c1g ^ (r1g & 7)) << 3);
  const int wb0 = w * 64 * 8;
  const int wb1 = wb0 + 256 * 8;

  // fragment-read swizzle
  const int swz  = l15 & 7;
  const int cks0 = ((0 * 4 + lh) ^ swz) << 3;
  const int cks1 = ((1 * 4 + lh) ^ swz) << 3;
  const int rfr  = l15 * 64;

  // stage one tile (4 gl16) into buffer slot bs
  auto stage = [&](int it, int bs) {
    const u16* kt = kb_g + (long)it * 64 * Hn;
    const u16* vp = vb_g + it * 64;
    gl16(kt + ksrc0, &kbuf[bs][wb0]);
    gl16(kt + ksrc1, &kbuf[bs][wb1]);
    gl16(vp + vsrc0, &vbuf[bs][wb0]);
    gl16(vp + vsrc1, &vbuf[bs][wb1]);
  };

  // compute one tile from buffer slot bs (QK -> exp2 -> PV, accumulating)
  auto tile_compute = [&](int bs) {
    const u16* kc  = &kbuf[bs][0];
    const u16* vcb = &vbuf[bs][0];

    f32x4 s0[4], s1[4];
    #pragma unroll
    for (int n = 0; n < 4; ++n) { s0[n] = f32x4{0.f,0.f,0.f,0.f}; s1[n] = f32x4{0.f,0.f,0.f,0.f}; }
    __builtin_amdgcn_s_setprio(1);
    #pragma unroll
    for (int n = 0; n < 4; ++n) {
      const short8 ak0 = *reinterpret_cast<const short8*>(&kc[n * 1024 + rfr + cks0]);
      const short8 ak1 = *reinterpret_cast<const short8*>(&kc[n * 1024 + rfr + cks1]);
      s0[n] = MFMA16(ak0, aq[0][0], s0[n]);
      s0[n] = MFMA16(ak1, aq[0][1], s0[n]);
      s1[n] = MFMA16(ak0, aq[1][0], s1[n]);
      s1[n] = MFMA16(ak1, aq[1][1], s1[n]);
    }
    __builtin_amdgcn_s_setprio(0);

    #pragma unroll
    for (int n = 0; n < 4; ++n)
      #pragma unroll
      for (int r = 0; r < 4; ++r) {
        s0[n][r] = __builtin_amdgcn_exp2f(s0[n][r]);
        s1[n][r] = __builtin_amdgcn_exp2f(s1[n][r]);
      }

    union { short8 s8; uint32_t u[4]; } B00, B01, B10, B11;
    B00.u[0] = pkbf(s0[0][0], s0[0][1]); B00.u[1] = pkbf(s0[0][2], s0[0][3]);
    B00.u[2] = pkbf(s0[1][0], s0[1][1]); B00.u[3] = pkbf(s0[1][2], s0[1][3]);
    B01.u[0] = pkbf(s0[2][0], s0[2][1]); B01.u[1] = pkbf(s0[2][2], s0[2][3]);
    B01.u[2] = pkbf(s0[3][0], s0[3][1]); B01.u[3] = pkbf(s0[3][2], s0[3][3]);
    B10.u[0] = pkbf(s1[0][0], s1[0][1]); B10.u[1] = pkbf(s1[0][2], s1[0][3]);
    B10.u[2] = pkbf(s1[1][0], s1[1][1]); B10.u[3] = pkbf(s1[1][2], s1[1][3]);
    B11.u[0] = pkbf(s1[2][0], s1[2][1]); B11.u[1] = pkbf(s1[2][2], s1[2][3]);
    B11.u[2] = pkbf(s1[3][0], s1[3][1]); B11.u[3] = pkbf(s1[3][2], s1[3][3]);

    __builtin_amdgcn_s_setprio(1);
    #pragma unroll
    for (int m = 0; m < 4; ++m) {
      const short8 av0 = *reinterpret_cast<const short8*>(&vcb[m * 1024 + rfr + cks0]);
      const short8 av1 = *reinterpret_cast<const short8*>(&vcb[m * 1024 + rfr + cks1]);
      o[0][m] = MFMA16(av0, B00.s8, o[0][m]);
      o[0][m] = MFMA16(av1, B01.s8, o[0][m]);
      o[1][m] = MFMA16(av0, B10.s8, o[1][m]);
      o[1][m] = MFMA16(av1, B11.s8, o[1][m]);
    }
    ls0 = MFMA16(ON.s8, B00.s8, ls0);
    ls0 = MFMA16(ON.s8, B01.s8, ls0);
    ls1 = MFMA16(ON.s8, B10.s8, ls1);
    ls1 = MFMA16(ON.s8, B11.s8, ls1);
    __builtin_amdgcn_s_setprio(0);
  };

  // prologue: stage tiles 0..3 into buffers 0..3 (16 gl16)
  stage(it0 + 0, 0);
  stage(it0 + 1, 1);
  stage(it0 + 2, 2);
  stage(it0 + 3, 3);
  asm volatile("s_waitcnt vmcnt(8)" ::: "memory");   // tiles 0,1 landed
  __builtin_amdgcn_s_barrier();
  __builtin_amdgcn_sched_barrier(0);

  for (int p = 0; p < 8; ++p) {
    const int bA = (2 * p) & 3;
    const int bB = (2 * p + 1) & 3;
    tile_compute(bA);
    tile_compute(bB);

    if (p < 7) {
      asm volatile("s_waitcnt vmcnt(0)" ::: "memory");  // pair p+1 landed
      __builtin_amdgcn_s_barrier();
      __builtin_amdgcn_sched_barrier(0);
      if (p < 6) {
        stage(it0 + 2 * p + 4, bA);   // refill just-freed buffers
        stage(it0 + 2 * p + 5, bB);
      }
    }
  }

  // epilogue: write BF16 unnormalized O-partials + f32 l
  #pragma unroll
  for (int qg = 0; qg < 2; ++qg) {
    const float tot = (qg == 0) ? ls0[0] : ls1[0];
    const long qrow = rowbase + w * 32 + qg * 16 + l15;
    u16* od = opart + ((long)split * NELT) + qrow * Hn;
    #pragma unroll
    for (int m = 0; m < 4; ++m) {
      uint32_t p0 = pkbf(o[qg][m][0], o[qg][m][1]);
      uint32_t p1 = pkbf(o[qg][m][2], o[qg][m][3]);
      uint32_t* dst = reinterpret_cast<uint32_t*>(od + m * 16 + lh * 4);
      dst[0] = p0; dst[1] = p1;
    }
    if (lh == 0) lpart[(long)split * NTOK + qrow] = tot;
  }
}

// ---------------------------------------------------------------------------
// Kernel 3: combine bf16 split-K partials: out = (sum O_s) / (sum l_s)
// 1024 blocks x 256 thr; 8 elems per thread.
// ---------------------------------------------------------------------------
__global__ __launch_bounds__(256) void combine(
    const u16* __restrict__ op, const float* __restrict__ lp,
    float* __restrict__ out)
{
  const long idx  = (long)blockIdx.x * 256 + threadIdx.x;
  const long base = idx * 8;
  const long row  = base >> 6;
  float lsum = 0.f;
  #pragma unroll
  for (int s = 0; s < SPLITS; ++s) lsum += lp[s * NTOK + row];
  const float linv = 1.0f / lsum;

  float acc[8] = {0.f, 0.f, 0.f, 0.f, 0.f, 0.f, 0.f, 0.f};
  #pragma unroll
  for (int s = 0; s < SPLITS; ++s) {
    union { short8 v; u16 u[8]; } pk;
    pk.v = *reinterpret_cast<const short8*>(op + s * NELT + base);
    #pragma unroll
    for (int j = 0; j < 8; ++j) {
      union { uint32_t u; float f; } c; c.u = ((uint32_t)pk.u[j]) << 16;
      acc[j] += c.f;
    }
  }
  float4 r0, r1;
  r0.x = acc[0] * linv; r0.y = acc[1] * linv; r0.z = acc[2] * linv; r0.w = acc[3] * linv;
  r1.x = acc[4] * linv; r1.y = acc[5] * linv; r1.z = acc[6] * linv; r1.w = acc[7] * linv;
  *reinterpret_cast<float4*>(out + base)     = r0;
  *reinterpret_cast<float4*>(out + base + 4) = r1;
}

// ---------------------------------------------------------------------------
extern "C" void kernel_launch(void* const* d_in, const int* in_sizes, int n_in,
                              void* d_out, int out_size, void* d_ws, size_t ws_size,
                              hipStream_t stream) {
  const float* x  = (const float*)d_in[0];
  const float* Wq = (const float*)d_in[1];
  const float* bq = (const float*)d_in[2];
  const float* Wk = (const float*)d_in[3];
  const float* bk = (const float*)d_in[4];
  const float* Wv = (const float*)d_in[5];
  const float* bv = (const float*)d_in[6];
  float* out = (float*)d_out;

  u16* qs  = (u16*)d_ws;                         // [32768][64] bf16, pre-scaled
  u16* ks  = qs + NELT;                          // [32768][64] bf16
  u16* vs  = ks + NELT;                          // V^T [16][64][2048] bf16 (PI-slot order)
  u16* wtd = vs + NELT;                          // WT [3][64][384] bf16
  u16* op  = wtd + 3 * 64 * Cn;                  // O partials [SPLITS][32768][64] bf16
  float* lp = (float*)(op + (long)SPLITS * NELT);// l partials [SPLITS][32768] f32

  hipLaunchKernelGGL(wtrans, dim3(18), dim3(256), 0, stream, Wq, Wk, Wv, wtd);
  hipLaunchKernelGGL(qkv_proj, dim3((int)(NTOK / 64)), dim3(256), 0, stream,
                     x, wtd, bq, bk, bv, qs, ks, vs);
  hipLaunchKernelGGL(flash_attn, dim3(16 * 16 * SPLITS), dim3(256), 0, stream,
                     qs, ks, vs, op, lp);
  hipLaunchKernelGGL(combine, dim3((int)(NELT / 8 / 256)), dim3(256), 0, stream,
                     op, lp, out);
}